// Round 13
// baseline (408.644 us; speedup 1.0000x reference)
//
#include <hip/hip_runtime.h>

#define H 128          // hidden dim (fixed by problem)
#define CAP 64         // max edges per (rel,dst) bucket

typedef _Float16 f16x8 __attribute__((ext_vector_type(8)));
typedef _Float16 f16x2 __attribute__((ext_vector_type(2)));
typedef float    f32x4 __attribute__((ext_vector_type(4)));

// ---------------- unified weight prep (one launch) --------------------------------
// range 0: wInT packed MFMA-B-fragment order (gemm B, proven layout)
// range 1: wcatT [col][384] = concat_k(W_root;W_0;W_1)^T (fused_l1 B)
// range 2: wfin[m][k][c] = W_m @ w_out (folded layer-2+projection)
// range 3: bfin = b_conv @ w_out + b_out
__global__ __launch_bounds__(256) void prep_all(const float* __restrict__ w_in,
    const float* __restrict__ w_root, const float* __restrict__ w_rel,
    const float* __restrict__ b_conv, const float* __restrict__ w_out,
    const float* __restrict__ b_out, _Float16* __restrict__ wInT,
    _Float16* __restrict__ wcatT, float* __restrict__ wfin,
    float* __restrict__ bfin, int K, int OUT)
{
    int idx = blockIdx.x * 256 + threadIdx.x;
    int tot1 = K * H;                                  // 98304
    if (idx < tot1) {
        int k = idx >> 7, c = idx & 127;               // coalesced read of w_in
        int o = ((k >> 3) << 10) + (c << 3) + (k & 7); // ((k/8)*H + c)*8 + k%8
        wInT[o] = (_Float16)w_in[idx];
        return;
    }
    int i2 = idx - tot1;
    if (i2 < H * 384) {
        int c = i2 / 384, k = i2 - c * 384;
        float v;
        if (k < 128)      v = w_root[(size_t)k * H + c];
        else if (k < 256) v = w_rel[(size_t)(k - 128) * H + c];
        else              v = w_rel[(size_t)H * H + (size_t)(k - 256) * H + c];
        wcatT[i2] = (_Float16)v;
        return;
    }
    int i3 = i2 - H * 384;
    int nw = 3 * H * OUT;
    if (i3 < nw) {
        int mk = i3 / OUT, c = i3 - mk * OUT;
        int m = mk >> 7, k = mk & 127;
        const float* W = (m == 0) ? w_root : (w_rel + (size_t)(m - 1) * H * H);
        float s = 0.f;
        for (int j = 0; j < H; j++)
            s += W[(size_t)k * H + j] * w_out[(size_t)j * OUT + c];
        wfin[(size_t)mk * OUT + c] = s;
    } else if (i3 < nw + OUT) {
        int c = i3 - nw;
        float s = b_out[c];
        for (int j = 0; j < H; j++) s += b_conv[j] * w_out[(size_t)j * OUT + c];
        bfin[c] = s;
    }
}

__device__ __forceinline__ f16x8 cvt8(float4 v0, float4 v1) {
    f16x8 t;
    t[0] = (_Float16)v0.x; t[1] = (_Float16)v0.y; t[2] = (_Float16)v0.z; t[3] = (_Float16)v0.w;
    t[4] = (_Float16)v1.x; t[5] = (_Float16)v1.y; t[6] = (_Float16)v1.z; t[7] = (_Float16)v1.w;
    return t;
}

// ---------------- combined: big MFMA GEMM (r9-verified) + edge bucketing ---------
// blockIdx < gemmBlocks : 64-row GEMM tile (global_load_lds staged).
// blockIdx >= gemmBlocks: 256-edge hist block overlapped under the GEMM's idle
// memory slack (r11-verified: saved ~20us vs serial hist_fill).
__global__ __launch_bounds__(256, 2) void gemm_hist(const float* __restrict__ A,
    const _Float16* __restrict__ WP, const float* __restrict__ bias,
    _Float16* __restrict__ C16, int M, int K, int ldc, int gemmBlocks,
    const int* __restrict__ esrc, const int* __restrict__ edst,
    const int* __restrict__ et, int* __restrict__ cnt, int* __restrict__ elist,
    int E, int N)
{
    __shared__ float As[2][4][2048];   // [buf][wave][16 rows x 128 cols fp32] = 64KB

    if ((int)blockIdx.x >= gemmBlocks) {
        int e = (blockIdx.x - gemmBlocks) * 256 + threadIdx.x;
        if (e < E) {
            int s = esrc[e], d = edst[e], t = et[e];
            int b = t * N + d;
            int pos = atomicAdd(&cnt[b], 1);
            if (pos < CAP)
                __builtin_nontemporal_store(s, &elist[(size_t)b * CAP + pos]);
        }
        return;
    }

    const int tid = threadIdx.x;
    const int w   = tid >> 6;
    const int l   = tid & 63;
    const int l15 = l & 15;
    const int q   = l >> 4;
    const int brow = blockIdx.x * 64;
    const int wr   = w * 16;

    const int lh  = l >> 5;            // row parity within a gll instr
    const int l31 = l & 31;            // physical 16B granule this lane fills

    const _Float16* bp = WP + ((size_t)q * H + l15) * 8;

    float bj[8];
#pragma unroll
    for (int j = 0; j < 8; j++) bj[j] = bias[j * 16 + l15];

    f32x4 acc[8];
    const f32x4 z4 = {0.f, 0.f, 0.f, 0.f};
#pragma unroll
    for (int j = 0; j < 8; j++) acc[j] = z4;

    const int chunks = K / 128;        // 6

#define STAGE(c, nbuf)                                                          \
    {                                                                           \
        _Pragma("unroll")                                                       \
        for (int i = 0; i < 8; i++) {                                           \
            int r  = 2 * i + lh;                                                \
            int gr = brow + wr + r; if (gr >= M) gr = M - 1;                    \
            int cg = l31 ^ (r & 7);                                             \
            const float* ga = A + (size_t)gr * K + (c) * 128 + cg * 4;          \
            __builtin_amdgcn_global_load_lds(                                   \
                (const __attribute__((address_space(1))) void*)ga,              \
                (__attribute__((address_space(3))) void*)&As[nbuf][w][i * 256], \
                16, 0, 0);                                                      \
        }                                                                       \
    }

    STAGE(0, 0);
    __syncthreads();

    for (int c = 0; c < chunks; c++) {
        if (c + 1 < chunks) STAGE(c + 1, (c + 1) & 1);

        const float* wbuf = As[c & 1][w];
#pragma unroll
        for (int ks = 0; ks < 4; ks++) {
            const int sl = ks * 4 + q;
            const int xr = l15 & 7;
            const int p0 = (2 * sl) ^ xr;
            const int p1 = (2 * sl + 1) ^ xr;
            float4 lo = *(const float4*)&wbuf[l15 * 128 + p0 * 4];
            float4 hi = *(const float4*)&wbuf[l15 * 128 + p1 * 4];
            f16x8 af = cvt8(lo, hi);
            const _Float16* bks = bp + (size_t)(c * 4 + ks) * 4096;
            f16x8 bf[8];
#pragma unroll
            for (int j = 0; j < 8; j++) bf[j] = *(const f16x8*)(bks + j * 128);
#pragma unroll
            for (int j = 0; j < 8; j++)
                acc[j] = __builtin_amdgcn_mfma_f32_16x16x32_f16(af, bf[j], acc[j], 0, 0, 0);
        }
        __syncthreads();
    }
#undef STAGE

#pragma unroll
    for (int rg = 0; rg < 4; rg++) {
        int row = brow + wr + q * 4 + rg;
        if (row < M) {
#pragma unroll
            for (int j = 0; j < 8; j++) {
                float v = acc[j][rg] + bj[j];
                v = (v >= 0.f) ? v : 0.01f * v;
                C16[(size_t)row * ldc + j * 16 + l15] = (_Float16)v;
            }
        }
    }
}

// ---------------- fused layer-1 + layer-2 projection -----------------------------
// Phase 1: gather relation means for 16 rows into LDS Ml (as r10-verified).
// Phase 2: concat GEMM for the tile IN REGISTERS (x2 never materialized), and
//   fold the 9-way projection (P = x2 @ [Wf_rel0|Wf_rel1|Wf_x]) into the fp32
//   epilogue: per lane 72 FMAs vs the L1-hot wfin, xor-reduce over the 16
//   col-lanes, LDS-atomic merge of the 8 col-fragments, 144 threads store P.
// Deletes proj9's launch + the 12.8MB X2 write + 12.8MB re-read; projection now
// uses pre-fp16-rounding values (closer to the fp32 reference).
__global__ __launch_bounds__(256) void fused_l1(const _Float16* __restrict__ X1,
    const _Float16* __restrict__ WT, const float* __restrict__ bias,
    const float* __restrict__ wfin, const int* __restrict__ elist,
    const int* __restrict__ cnt, float* __restrict__ P, int N)
{
    __shared__ _Float16 Ml[16][264];
    __shared__ float Pl[16][9];

    const int tid = threadIdx.x;
    const int w   = tid >> 6;
    const int l   = tid & 63;
    const int l15 = l & 15;
    const int q   = l >> 4;
    const int r0  = blockIdx.x * 16;

    const int eo   = l >> 4;
    const int e2   = eo & 1;
    const int half = l >> 5;              // 0: rel0, 1: rel1
    const int c8   = l15 * 8;

    if (tid < 144) Pl[tid / 9][tid % 9] = 0.f;

    // ---- phase 1: gather 4 rows per wave ----
    const f16x8 zv = {};
#pragma unroll
    for (int i = 0; i < 4; i++) {
        const int rl = w * 4 + i;
        const int r  = r0 + rl;           // wave-uniform
        float acc[8];
#pragma unroll
        for (int j = 0; j < 8; j++) acc[j] = 0.f;
        float inv = 0.f;
        if (r < N) {
            int dr = cnt[(size_t)half * N + r];
            int d  = dr < CAP ? dr : CAP;
            inv = dr > 0 ? 1.f / (float)dr : 0.f;
            const int* lst = elist + ((size_t)half * N + r) * CAP;
            for (int p = e2; p < d; p += 8) {
                int p1 = p + 2, p2 = p + 4, p3 = p + 6;
                int s0 = lst[p];
                f16x8 v0 = *(const f16x8*)&X1[(size_t)s0 * H + c8];
                f16x8 v1 = zv, v2 = zv, v3 = zv;
                if (p1 < d) { int s = lst[p1]; v1 = *(const f16x8*)&X1[(size_t)s * H + c8]; }
                if (p2 < d) { int s = lst[p2]; v2 = *(const f16x8*)&X1[(size_t)s * H + c8]; }
                if (p3 < d) { int s = lst[p3]; v3 = *(const f16x8*)&X1[(size_t)s * H + c8]; }
#pragma unroll
                for (int j = 0; j < 8; j++)
                    acc[j] += (float)v0[j] + (float)v1[j] + (float)v2[j] + (float)v3[j];
            }
        }
#pragma unroll
        for (int j = 0; j < 8; j++) {
            acc[j] += __shfl_xor(acc[j], 16);
            acc[j] *= inv;
        }
        if (r < N && (eo == 0 || eo == 2)) {
            f16x8 o;
#pragma unroll
            for (int j = 0; j < 8; j++) o[j] = (_Float16)acc[j];
            *(f16x8*)&Ml[rl][half * 128 + c8] = o;
        }
    }
    __syncthreads();   // Ml ready; also covers the Pl zero-init

    // ---- phase 2: concat GEMM in regs + folded projection ----
    int gr = r0 + l15; if (gr >= N) gr = N - 1;
    f16x8 xf[12];
    {
        const _Float16* xp = X1 + (size_t)gr * H + q * 8;
#pragma unroll
        for (int c = 0; c < 4; c++) xf[c] = *(const f16x8*)(xp + c * 32);
#pragma unroll
        for (int c = 4; c < 12; c++) xf[c] = *(const f16x8*)&Ml[l15][(c - 4) * 32 + q * 8];
    }

    // pp[rg][0..2]=rel0 (m=1), [3..5]=rel1 (m=2), [6..8]=x (m=0)
    float pp[4][9];
#pragma unroll
    for (int rg = 0; rg < 4; rg++)
#pragma unroll
        for (int c = 0; c < 9; c++) pp[rg][c] = 0.f;

    const f32x4 z4 = {0.f, 0.f, 0.f, 0.f};
#pragma unroll
    for (int cf = 0; cf < 2; cf++) {
        const int col = w * 32 + cf * 16 + l15;
        f16x8 bf[12];
        const _Float16* wpp = WT + (size_t)col * 384 + q * 8;
#pragma unroll
        for (int c = 0; c < 12; c++) bf[c] = *(const f16x8*)(wpp + c * 32);
        f32x4 a0 = z4;
#pragma unroll
        for (int c = 0; c < 12; c++)
            a0 = __builtin_amdgcn_mfma_f32_16x16x32_f16(xf[c], bf[c], a0, 0, 0, 0);
        const float bj = bias[col];
        const float* w0 = wfin + (size_t)(0 * H + col) * 3;   // x slice
        const float* w1 = wfin + (size_t)(1 * H + col) * 3;   // rel0 slice
        const float* w2 = wfin + (size_t)(2 * H + col) * 3;   // rel1 slice
#pragma unroll
        for (int rg = 0; rg < 4; rg++) {
            float v = a0[rg] + bj;        // x2 value, fp32 (pre-rounding)
#pragma unroll
            for (int c3 = 0; c3 < 3; c3++) {
                pp[rg][c3]     += v * w1[c3];
                pp[rg][3 + c3] += v * w2[c3];
                pp[rg][6 + c3] += v * w0[c3];
            }
        }
    }

    // reduce over the 16 col-lanes of each q-group (bits 0..3 only)
#pragma unroll
    for (int rg = 0; rg < 4; rg++)
#pragma unroll
        for (int c = 0; c < 9; c++) {
            pp[rg][c] += __shfl_xor(pp[rg][c], 1);
            pp[rg][c] += __shfl_xor(pp[rg][c], 2);
            pp[rg][c] += __shfl_xor(pp[rg][c], 4);
            pp[rg][c] += __shfl_xor(pp[rg][c], 8);
        }
    if (l15 < 9) {
        const int c = l15;
#pragma unroll
        for (int rg = 0; rg < 4; rg++)
            atomicAdd(&Pl[q * 4 + rg][c], pp[rg][c]);
    }
    __syncthreads();

    if (tid < 144) {
        int rl = tid / 9, c = tid % 9;
        int row = r0 + rl;
        if (row < N) {
            int slice = (c < 3) ? 0 : (c < 6) ? 4 : 8;
            int cc    = (c < 3) ? c : (c < 6) ? c - 3 : c - 6;
            P[(size_t)row * 12 + slice + cc] = Pl[rl][c];
        }
    }
}

// ---------------- gather_fin: out[dst] = P_x[dst] + sum_r mean(P_r[src]) + bfin ---
// One thread per dst; 16B float4 per edge from the 2.4MB L2-resident P table;
// 4-deep unroll for MLP.
__global__ __launch_bounds__(256) void gather_fin(const float* __restrict__ P,
    const int* __restrict__ elist, const int* __restrict__ cnt,
    const float* __restrict__ bfin, float* __restrict__ out, int N)
{
    int i = blockIdx.x * 256 + threadIdx.x;
    if (i >= N) return;

    float o0 = P[(size_t)i * 12 + 8] + bfin[0];
    float o1 = P[(size_t)i * 12 + 9] + bfin[1];
    float o2 = P[(size_t)i * 12 + 10] + bfin[2];

#pragma unroll
    for (int r = 0; r < 2; r++) {
        int dr = cnt[(size_t)r * N + i];
        int d  = dr < CAP ? dr : CAP;
        float inv = dr > 0 ? 1.f / (float)dr : 0.f;
        const int* lst = elist + ((size_t)r * N + i) * CAP;
        float s0 = 0.f, s1 = 0.f, s2 = 0.f;
        int p = 0;
        for (; p + 3 < d; p += 4) {
            int a = lst[p], b = lst[p + 1], c = lst[p + 2], e = lst[p + 3];
            float4 va = *(const float4*)&P[(size_t)a * 12 + r * 4];
            float4 vb = *(const float4*)&P[(size_t)b * 12 + r * 4];
            float4 vc = *(const float4*)&P[(size_t)c * 12 + r * 4];
            float4 ve = *(const float4*)&P[(size_t)e * 12 + r * 4];
            s0 += va.x + vb.x + vc.x + ve.x;
            s1 += va.y + vb.y + vc.y + ve.y;
            s2 += va.z + vb.z + vc.z + ve.z;
        }
        for (; p < d; p++) {
            int a = lst[p];
            float4 va = *(const float4*)&P[(size_t)a * 12 + r * 4];
            s0 += va.x; s1 += va.y; s2 += va.z;
        }
        o0 += s0 * inv; o1 += s1 * inv; o2 += s2 * inv;
    }
    out[(size_t)i * 3 + 0] = o0;
    out[(size_t)i * 3 + 1] = o1;
    out[(size_t)i * 3 + 2] = o2;
}

// ---------------- raw-x gather (fallback path, MODE 0 only) ----------------------
template<int MODE>
__global__ __launch_bounds__(256) void gather_k(const _Float16* __restrict__ X,
    int ldx, _Float16* __restrict__ Mout, const int* __restrict__ elist,
    const int* __restrict__ cnt, int N,
    const float* __restrict__ wfin, const float* __restrict__ bfin,
    float* __restrict__ out)
{
    int wv = blockIdx.x * 4 + (threadIdx.x >> 6);
    int l  = threadIdx.x & 63;
    if (wv >= N) return;

    const int eo   = l >> 4;
    const int e2   = eo & 1;
    const int half = l >> 5;
    const int c8   = (l & 15) * 8;

    int dr = cnt[(size_t)half * N + wv];
    int d  = dr < CAP ? dr : CAP;
    float inv = dr > 0 ? 1.f / (float)dr : 0.f;
    const int* lst = elist + ((size_t)half * N + wv) * CAP;

    float acc[8];
#pragma unroll
    for (int j = 0; j < 8; j++) acc[j] = 0.f;

    const f16x8 zv = {};
    for (int p = e2; p < d; p += 8) {
        int p1 = p + 2, p2 = p + 4, p3 = p + 6;
        int s0 = lst[p];
        f16x8 v0 = *(const f16x8*)&X[(size_t)s0 * ldx + c8];
        f16x8 v1 = zv, v2 = zv, v3 = zv;
        if (p1 < d) { int s = lst[p1]; v1 = *(const f16x8*)&X[(size_t)s * ldx + c8]; }
        if (p2 < d) { int s = lst[p2]; v2 = *(const f16x8*)&X[(size_t)s * ldx + c8]; }
        if (p3 < d) { int s = lst[p3]; v3 = *(const f16x8*)&X[(size_t)s * ldx + c8]; }
#pragma unroll
        for (int j = 0; j < 8; j++)
            acc[j] += (float)v0[j] + (float)v1[j] + (float)v2[j] + (float)v3[j];
    }

#pragma unroll
    for (int j = 0; j < 8; j++) {
        acc[j] += __shfl_xor(acc[j], 16);
        acc[j] *= inv;
    }

    if (MODE == 0) {
        if (eo == 0 || eo == 2) {
            f16x8 o;
#pragma unroll
            for (int j = 0; j < 8; j++) o[j] = (_Float16)acc[j];
            *(f16x8*)&Mout[(size_t)wv * 256 + half * 128 + c8] = o;
        }
    }
}

// ---------------- concat GEMM (fallback path, OUT != 3) --------------------------
__global__ __launch_bounds__(512) void gemm_cat(const _Float16* __restrict__ X1,
    const _Float16* __restrict__ Mt, const _Float16* __restrict__ WT,
    const float* __restrict__ bias, _Float16* __restrict__ X2, int M, int mtiles)
{
    const int w   = threadIdx.x >> 6;
    const int l   = threadIdx.x & 63;
    const int l15 = l & 15;
    const int q   = l >> 4;
    const int col = w * 16 + l15;

    f16x8 bf[12];
    {
        const _Float16* wpp = WT + (size_t)col * 384 + q * 8;
#pragma unroll
        for (int c = 0; c < 12; c++) bf[c] = *(const f16x8*)(wpp + c * 32);
    }
    const float bj = bias[col];

    int t = blockIdx.x;
    if (t >= mtiles) return;
    f16x8 xf[12];
    {
        const _Float16* xp = X1 + ((size_t)t * 16 + l15) * 128 + q * 8;
        const _Float16* mp = Mt + ((size_t)t * 16 + l15) * 256 + q * 8;
#pragma unroll
        for (int c = 0; c < 4; c++) xf[c] = *(const f16x8*)(xp + c * 32);
#pragma unroll
        for (int c = 4; c < 12; c++) xf[c] = *(const f16x8*)(mp + (c - 4) * 32);
    }

    const f32x4 z4 = {0.f, 0.f, 0.f, 0.f};
    while (true) {
        int tn = t + gridDim.x;
        bool more = tn < mtiles;
        f16x8 xnf[12];
        if (more) {
            const _Float16* xp = X1 + ((size_t)tn * 16 + l15) * 128 + q * 8;
            const _Float16* mp = Mt + ((size_t)tn * 16 + l15) * 256 + q * 8;
#pragma unroll
            for (int c = 0; c < 4; c++) xnf[c] = *(const f16x8*)(xp + c * 32);
#pragma unroll
            for (int c = 4; c < 12; c++) xnf[c] = *(const f16x8*)(mp + (c - 4) * 32);
        }

        f32x4 a0 = z4;
#pragma unroll
        for (int c = 0; c < 12; c++)
            a0 = __builtin_amdgcn_mfma_f32_16x16x32_f16(xf[c], bf[c], a0, 0, 0, 0);

#pragma unroll
        for (int rg = 0; rg < 4; rg++) {
            int row = t * 16 + q * 4 + rg;
            if (row < M) X2[(size_t)row * 128 + col] = (_Float16)(a0[rg] + bj);
        }
        if (!more) break;
        t = tn;
#pragma unroll
        for (int c = 0; c < 12; c++) xf[c] = xnf[c];
    }
}

// ---------------- generic projection fallback (OUT != 3) -------------------------
__global__ __launch_bounds__(256) void proj_generic(const _Float16* __restrict__ X2,
    const _Float16* __restrict__ Mt, const float* __restrict__ wfin,
    const float* __restrict__ bfin, float* __restrict__ out, int N, int OUT)
{
    int row = blockIdx.x * 4 + (threadIdx.x >> 6);
    int l = threadIdx.x & 63;
    if (row >= N) return;
    float xv[6];
#pragma unroll
    for (int i = 0; i < 6; i++) {
        int k = l * 6 + i;
        xv[i] = (k < 128) ? (float)X2[(size_t)row * 128 + k]
                          : (float)Mt[(size_t)row * 256 + (k - 128)];
    }
    for (int c = 0; c < OUT; c++) {
        float p = 0.f;
#pragma unroll
        for (int i = 0; i < 6; i++) p += xv[i] * wfin[(size_t)(l * 6 + i) * OUT + c];
        for (int off = 32; off > 0; off >>= 1) p += __shfl_down(p, off);
        if (l == 0) out[(size_t)row * OUT + c] = p + bfin[c];
    }
}

extern "C" void kernel_launch(void* const* d_in, const int* in_sizes, int n_in,
                              void* d_out, int out_size, void* d_ws, size_t ws_size,
                              hipStream_t stream) {
    const float* feature = (const float*)d_in[0];
    const int*   ei      = (const int*)d_in[1];   // [2,E]: src then dst
    const int*   et      = (const int*)d_in[2];   // [E]
    const float* w_in    = (const float*)d_in[3];
    const float* b_in    = (const float*)d_in[4];
    const float* w_rel   = (const float*)d_in[5];
    const float* w_root  = (const float*)d_in[6];
    const float* b_conv  = (const float*)d_in[7];
    const float* w_out   = (const float*)d_in[8];
    const float* b_out   = (const float*)d_in[9];

    const int HH   = in_sizes[4];                 // 128
    const int D_IN = in_sizes[3] / HH;            // 768
    const int N    = in_sizes[0] / D_IN;          // 50000
    const int E    = in_sizes[1] / 2;             // 600000
    const int OUT  = in_sizes[9];                 // 3

    // workspace layout (16B-aligned segments)
    char* base = (char*)d_ws;
    _Float16* wInT  = (_Float16*)base;                             // 768*128 packed
    _Float16* wcatT = wInT + (size_t)D_IN * HH;                    // 128*384
    _Float16* X1    = wcatT + (size_t)HH * 384;                    // N*128
    _Float16* X2    = X1 + (size_t)N * HH;                         // N*128 (fallback only)
    _Float16* Mt    = X2 + (size_t)N * HH;                         // N*256 (fallback only)
    float* Pt       = (float*)(Mt + (size_t)N * 256);              // N*12 fp32
    float* wfin     = Pt + (size_t)N * 12;                         // 3*128*OUT
    float* bfin     = wfin + (size_t)3 * HH * (OUT > 0 ? OUT : 1); // OUT
    int* cnt        = (int*)(bfin + ((OUT + 3) & ~3));             // 2N
    int* elist      = cnt + (size_t)2 * N;                         // 2N*CAP

    hipMemsetAsync(cnt, 0, sizeof(int) * (size_t)2 * N, stream);
    {
        int ptot = D_IN * HH + HH * 384 + 3 * HH * OUT + OUT;
        prep_all<<<(ptot + 255) / 256, 256, 0, stream>>>(
            w_in, w_root, w_rel, b_conv, w_out, b_out,
            wInT, wcatT, wfin, bfin, D_IN, OUT);
    }

    // combined launch: GEMM tiles first (long pole), hist blocks overlapped behind
    const int gemmBlocks = (N + 63) / 64;
    const int histBlocks = (E + 255) / 256;
    gemm_hist<<<gemmBlocks + histBlocks, 256, 0, stream>>>(
        feature, wInT, b_in, X1, N, D_IN, HH, gemmBlocks,
        ei, ei + E, et, cnt, elist, E, N);

    const int mtiles  = (N + 15) / 16;
    const int gblocks = (N + 3) / 4;

    if (OUT == 3) {
        // layer 1 GEMM-gather + layer-2 projection fused; then 16B/edge gather
        fused_l1<<<mtiles, 256, 0, stream>>>(X1, wcatT, b_conv, wfin,
                                             elist, cnt, Pt, N);
        gather_fin<<<(N + 255) / 256, 256, 0, stream>>>(Pt, elist, cnt, bfin,
                                                        (float*)d_out, N);
    } else {
        gather_k<0><<<gblocks, 256, 0, stream>>>(X1, 128, Mt, elist, cnt, N,
                                                 nullptr, nullptr, nullptr);
        gemm_cat<<<1024, 512, 0, stream>>>(X1, Mt, wcatT, b_conv, X2, N, mtiles);
        gather_k<0><<<gblocks, 256, 0, stream>>>(X2, 128, Mt, elist, cnt, N,
                                                 nullptr, nullptr, nullptr);
        proj_generic<<<gblocks, 256, 0, stream>>>(X2, Mt, wfin, bfin,
                                                  (float*)d_out, N, OUT);
    }
}

// Round 14
// 386.405 us; speedup vs baseline: 1.0576x; 1.0576x over previous
//
#include <hip/hip_runtime.h>

#define H 128          // hidden dim (fixed by problem)
#define CAP 64         // max edges per (rel,dst) bucket

typedef _Float16 f16x8 __attribute__((ext_vector_type(8)));
typedef _Float16 f16x2 __attribute__((ext_vector_type(2)));
typedef float    f32x4 __attribute__((ext_vector_type(4)));

// ---------------- unified weight prep (one launch) --------------------------------
// range 0: wInT packed MFMA-B-fragment order (gemm B, proven layout)
// range 1: wcatT [col][384] = concat_k(W_root;W_0;W_1)^T (fused_l1 B)
// range 2: wfin[m][k][c] = W_m @ w_out (folded layer-2+projection)
// range 3: bfin = b_conv @ w_out + b_out
__global__ __launch_bounds__(256) void prep_all(const float* __restrict__ w_in,
    const float* __restrict__ w_root, const float* __restrict__ w_rel,
    const float* __restrict__ b_conv, const float* __restrict__ w_out,
    const float* __restrict__ b_out, _Float16* __restrict__ wInT,
    _Float16* __restrict__ wcatT, float* __restrict__ wfin,
    float* __restrict__ bfin, int K, int OUT)
{
    int idx = blockIdx.x * 256 + threadIdx.x;
    int tot1 = K * H;                                  // 98304
    if (idx < tot1) {
        int k = idx >> 7, c = idx & 127;               // coalesced read of w_in
        int o = ((k >> 3) << 10) + (c << 3) + (k & 7); // ((k/8)*H + c)*8 + k%8
        wInT[o] = (_Float16)w_in[idx];
        return;
    }
    int i2 = idx - tot1;
    if (i2 < H * 384) {
        int c = i2 / 384, k = i2 - c * 384;
        float v;
        if (k < 128)      v = w_root[(size_t)k * H + c];
        else if (k < 256) v = w_rel[(size_t)(k - 128) * H + c];
        else              v = w_rel[(size_t)H * H + (size_t)(k - 256) * H + c];
        wcatT[i2] = (_Float16)v;
        return;
    }
    int i3 = i2 - H * 384;
    int nw = 3 * H * OUT;
    if (i3 < nw) {
        int mk = i3 / OUT, c = i3 - mk * OUT;
        int m = mk >> 7, k = mk & 127;
        const float* W = (m == 0) ? w_root : (w_rel + (size_t)(m - 1) * H * H);
        float s = 0.f;
        for (int j = 0; j < H; j++)
            s += W[(size_t)k * H + j] * w_out[(size_t)j * OUT + c];
        wfin[(size_t)mk * OUT + c] = s;
    } else if (i3 < nw + OUT) {
        int c = i3 - nw;
        float s = b_out[c];
        for (int j = 0; j < H; j++) s += b_conv[j] * w_out[(size_t)j * OUT + c];
        bfin[c] = s;
    }
}

__device__ __forceinline__ f16x8 cvt8(float4 v0, float4 v1) {
    f16x8 t;
    t[0] = (_Float16)v0.x; t[1] = (_Float16)v0.y; t[2] = (_Float16)v0.z; t[3] = (_Float16)v0.w;
    t[4] = (_Float16)v1.x; t[5] = (_Float16)v1.y; t[6] = (_Float16)v1.z; t[7] = (_Float16)v1.w;
    return t;
}

// ---------------- combined: big MFMA GEMM (r9-verified) + edge bucketing ---------
// blockIdx < gemmBlocks : 64-row GEMM tile (global_load_lds staged).
// blockIdx >= gemmBlocks: 256-edge hist block overlapped under the GEMM's idle
// memory slack (r11-verified: saved ~20us vs serial hist_fill).
__global__ __launch_bounds__(256, 2) void gemm_hist(const float* __restrict__ A,
    const _Float16* __restrict__ WP, const float* __restrict__ bias,
    _Float16* __restrict__ C16, int M, int K, int ldc, int gemmBlocks,
    const int* __restrict__ esrc, const int* __restrict__ edst,
    const int* __restrict__ et, int* __restrict__ cnt, int* __restrict__ elist,
    int E, int N)
{
    __shared__ float As[2][4][2048];   // [buf][wave][16 rows x 128 cols fp32] = 64KB

    if ((int)blockIdx.x >= gemmBlocks) {
        int e = (blockIdx.x - gemmBlocks) * 256 + threadIdx.x;
        if (e < E) {
            int s = esrc[e], d = edst[e], t = et[e];
            int b = t * N + d;
            int pos = atomicAdd(&cnt[b], 1);
            if (pos < CAP)
                __builtin_nontemporal_store(s, &elist[(size_t)b * CAP + pos]);
        }
        return;
    }

    const int tid = threadIdx.x;
    const int w   = tid >> 6;
    const int l   = tid & 63;
    const int l15 = l & 15;
    const int q   = l >> 4;
    const int brow = blockIdx.x * 64;
    const int wr   = w * 16;

    const int lh  = l >> 5;            // row parity within a gll instr
    const int l31 = l & 31;            // physical 16B granule this lane fills

    const _Float16* bp = WP + ((size_t)q * H + l15) * 8;

    float bj[8];
#pragma unroll
    for (int j = 0; j < 8; j++) bj[j] = bias[j * 16 + l15];

    f32x4 acc[8];
    const f32x4 z4 = {0.f, 0.f, 0.f, 0.f};
#pragma unroll
    for (int j = 0; j < 8; j++) acc[j] = z4;

    const int chunks = K / 128;        // 6

#define STAGE(c, nbuf)                                                          \
    {                                                                           \
        _Pragma("unroll")                                                       \
        for (int i = 0; i < 8; i++) {                                           \
            int r  = 2 * i + lh;                                                \
            int gr = brow + wr + r; if (gr >= M) gr = M - 1;                    \
            int cg = l31 ^ (r & 7);                                             \
            const float* ga = A + (size_t)gr * K + (c) * 128 + cg * 4;          \
            __builtin_amdgcn_global_load_lds(                                   \
                (const __attribute__((address_space(1))) void*)ga,              \
                (__attribute__((address_space(3))) void*)&As[nbuf][w][i * 256], \
                16, 0, 0);                                                      \
        }                                                                       \
    }

    STAGE(0, 0);
    __syncthreads();

    for (int c = 0; c < chunks; c++) {
        if (c + 1 < chunks) STAGE(c + 1, (c + 1) & 1);

        const float* wbuf = As[c & 1][w];
#pragma unroll
        for (int ks = 0; ks < 4; ks++) {
            const int sl = ks * 4 + q;
            const int xr = l15 & 7;
            const int p0 = (2 * sl) ^ xr;
            const int p1 = (2 * sl + 1) ^ xr;
            float4 lo = *(const float4*)&wbuf[l15 * 128 + p0 * 4];
            float4 hi = *(const float4*)&wbuf[l15 * 128 + p1 * 4];
            f16x8 af = cvt8(lo, hi);
            const _Float16* bks = bp + (size_t)(c * 4 + ks) * 4096;
            f16x8 bf[8];
#pragma unroll
            for (int j = 0; j < 8; j++) bf[j] = *(const f16x8*)(bks + j * 128);
#pragma unroll
            for (int j = 0; j < 8; j++)
                acc[j] = __builtin_amdgcn_mfma_f32_16x16x32_f16(af, bf[j], acc[j], 0, 0, 0);
        }
        __syncthreads();
    }
#undef STAGE

#pragma unroll
    for (int rg = 0; rg < 4; rg++) {
        int row = brow + wr + q * 4 + rg;
        if (row < M) {
#pragma unroll
            for (int j = 0; j < 8; j++) {
                float v = acc[j][rg] + bj[j];
                v = (v >= 0.f) ? v : 0.01f * v;
                C16[(size_t)row * ldc + j * 16 + l15] = (_Float16)v;
            }
        }
    }
}

// ---------------- fused layer-1 + layer-2 projection (spill-free v3) -------------
// r13 post-mortem: folding the projection through registers (pp[4][9] on top of
// xf[12]+bf[12]) needed ~130 live VGPRs; compiler allocated 60 and SPILLED —
// 114.8MB deterministic scratch writes, fused_l1 124us. v3 keeps the fusion but
// routes x2 through LDS: phase 2a = r11's proven concat-GEMM writing the fp32
// x2 tile to X2l[16][132]; phase 2b = register-light projection (16 lanes/row,
// 8 cols/lane, pp[9] only, shfl_xor group reduce). No atomics, no spills.
__global__ __launch_bounds__(256) void fused_l1(const _Float16* __restrict__ X1,
    const _Float16* __restrict__ WT, const float* __restrict__ bias,
    const float* __restrict__ wfin, const int* __restrict__ elist,
    const int* __restrict__ cnt, float* __restrict__ P, int N)
{
    __shared__ _Float16 Ml[16][264];
    __shared__ float X2l[16][132];

    const int tid = threadIdx.x;
    const int w   = tid >> 6;
    const int l   = tid & 63;
    const int l15 = l & 15;
    const int q   = l >> 4;
    const int r0  = blockIdx.x * 16;

    const int eo   = l >> 4;
    const int e2   = eo & 1;
    const int half = l >> 5;              // 0: rel0, 1: rel1
    const int c8   = l15 * 8;

    // ---- phase 1: gather 4 rows per wave ----
    const f16x8 zv = {};
#pragma unroll
    for (int i = 0; i < 4; i++) {
        const int rl = w * 4 + i;
        const int r  = r0 + rl;           // wave-uniform
        float acc[8];
#pragma unroll
        for (int j = 0; j < 8; j++) acc[j] = 0.f;
        float inv = 0.f;
        if (r < N) {
            int dr = cnt[(size_t)half * N + r];
            int d  = dr < CAP ? dr : CAP;
            inv = dr > 0 ? 1.f / (float)dr : 0.f;
            const int* lst = elist + ((size_t)half * N + r) * CAP;
            for (int p = e2; p < d; p += 8) {
                int p1 = p + 2, p2 = p + 4, p3 = p + 6;
                int s0 = lst[p];
                f16x8 v0 = *(const f16x8*)&X1[(size_t)s0 * H + c8];
                f16x8 v1 = zv, v2 = zv, v3 = zv;
                if (p1 < d) { int s = lst[p1]; v1 = *(const f16x8*)&X1[(size_t)s * H + c8]; }
                if (p2 < d) { int s = lst[p2]; v2 = *(const f16x8*)&X1[(size_t)s * H + c8]; }
                if (p3 < d) { int s = lst[p3]; v3 = *(const f16x8*)&X1[(size_t)s * H + c8]; }
#pragma unroll
                for (int j = 0; j < 8; j++)
                    acc[j] += (float)v0[j] + (float)v1[j] + (float)v2[j] + (float)v3[j];
            }
        }
#pragma unroll
        for (int j = 0; j < 8; j++) {
            acc[j] += __shfl_xor(acc[j], 16);
            acc[j] *= inv;
        }
        if (r < N && (eo == 0 || eo == 2)) {
            f16x8 o;
#pragma unroll
            for (int j = 0; j < 8; j++) o[j] = (_Float16)acc[j];
            *(f16x8*)&Ml[rl][half * 128 + c8] = o;
        }
    }
    __syncthreads();   // Ml ready

    // ---- phase 2a: concat GEMM in regs, x2 (fp32) -> LDS ----
    int gr = r0 + l15; if (gr >= N) gr = N - 1;
    f16x8 xf[12];
    {
        const _Float16* xp = X1 + (size_t)gr * H + q * 8;
#pragma unroll
        for (int c = 0; c < 4; c++) xf[c] = *(const f16x8*)(xp + c * 32);
#pragma unroll
        for (int c = 4; c < 12; c++) xf[c] = *(const f16x8*)&Ml[l15][(c - 4) * 32 + q * 8];
    }

    const f32x4 z4 = {0.f, 0.f, 0.f, 0.f};
#pragma unroll
    for (int cf = 0; cf < 2; cf++) {
        const int col = w * 32 + cf * 16 + l15;
        f16x8 bf[12];
        const _Float16* wpp = WT + (size_t)col * 384 + q * 8;
#pragma unroll
        for (int c = 0; c < 12; c++) bf[c] = *(const f16x8*)(wpp + c * 32);
        f32x4 a0 = z4;
#pragma unroll
        for (int c = 0; c < 12; c++)
            a0 = __builtin_amdgcn_mfma_f32_16x16x32_f16(xf[c], bf[c], a0, 0, 0, 0);
        const float bj = bias[col];
#pragma unroll
        for (int rg = 0; rg < 4; rg++)
            X2l[q * 4 + rg][col] = a0[rg] + bj;
    }
    __syncthreads();   // x2 tile ready

    // ---- phase 2b: 9-way projection from LDS (register-light) ----
    {
        const int rl  = tid >> 4;          // row 0..15
        const int k8  = (tid & 15) * 8;    // 8-col slice
        float pp[9];
#pragma unroll
        for (int c = 0; c < 9; c++) pp[c] = 0.f;
#pragma unroll
        for (int j = 0; j < 8; j++) {
            float v = X2l[rl][k8 + j];
            const float* w0 = wfin + (size_t)(0 * H + k8 + j) * 3;   // x slice
            const float* w1 = wfin + (size_t)(1 * H + k8 + j) * 3;   // rel0
            const float* w2 = wfin + (size_t)(2 * H + k8 + j) * 3;   // rel1
#pragma unroll
            for (int c3 = 0; c3 < 3; c3++) {
                pp[c3]     += v * w1[c3];
                pp[3 + c3] += v * w2[c3];
                pp[6 + c3] += v * w0[c3];
            }
        }
        // reduce across the 16 lanes of this row group (bits 0..3, convergent)
#pragma unroll
        for (int c = 0; c < 9; c++) {
            pp[c] += __shfl_xor(pp[c], 1);
            pp[c] += __shfl_xor(pp[c], 2);
            pp[c] += __shfl_xor(pp[c], 4);
            pp[c] += __shfl_xor(pp[c], 8);
        }
        if ((tid & 15) == 0) {
            int row = r0 + rl;
            if (row < N) {
                float* pr = P + (size_t)row * 12;
#pragma unroll
                for (int c3 = 0; c3 < 3; c3++) {
                    pr[c3]     = pp[c3];        // rel0 slice @ +0
                    pr[4 + c3] = pp[3 + c3];    // rel1 slice @ +16
                    pr[8 + c3] = pp[6 + c3];    // x slice    @ +32
                }
            }
        }
    }
}

// ---------------- gather_fin: out[dst] = P_x[dst] + sum_r mean(P_r[src]) + bfin ---
// One thread per dst; 16B float4 per edge from the 2.4MB L2-resident P table;
// 4-deep unroll for MLP.
__global__ __launch_bounds__(256) void gather_fin(const float* __restrict__ P,
    const int* __restrict__ elist, const int* __restrict__ cnt,
    const float* __restrict__ bfin, float* __restrict__ out, int N)
{
    int i = blockIdx.x * 256 + threadIdx.x;
    if (i >= N) return;

    float o0 = P[(size_t)i * 12 + 8] + bfin[0];
    float o1 = P[(size_t)i * 12 + 9] + bfin[1];
    float o2 = P[(size_t)i * 12 + 10] + bfin[2];

#pragma unroll
    for (int r = 0; r < 2; r++) {
        int dr = cnt[(size_t)r * N + i];
        int d  = dr < CAP ? dr : CAP;
        float inv = dr > 0 ? 1.f / (float)dr : 0.f;
        const int* lst = elist + ((size_t)r * N + i) * CAP;
        float s0 = 0.f, s1 = 0.f, s2 = 0.f;
        int p = 0;
        for (; p + 3 < d; p += 4) {
            int a = lst[p], b = lst[p + 1], c = lst[p + 2], e = lst[p + 3];
            float4 va = *(const float4*)&P[(size_t)a * 12 + r * 4];
            float4 vb = *(const float4*)&P[(size_t)b * 12 + r * 4];
            float4 vc = *(const float4*)&P[(size_t)c * 12 + r * 4];
            float4 ve = *(const float4*)&P[(size_t)e * 12 + r * 4];
            s0 += va.x + vb.x + vc.x + ve.x;
            s1 += va.y + vb.y + vc.y + ve.y;
            s2 += va.z + vb.z + vc.z + ve.z;
        }
        for (; p < d; p++) {
            int a = lst[p];
            float4 va = *(const float4*)&P[(size_t)a * 12 + r * 4];
            s0 += va.x; s1 += va.y; s2 += va.z;
        }
        o0 += s0 * inv; o1 += s1 * inv; o2 += s2 * inv;
    }
    out[(size_t)i * 3 + 0] = o0;
    out[(size_t)i * 3 + 1] = o1;
    out[(size_t)i * 3 + 2] = o2;
}

// ---------------- raw-x gather (fallback path, MODE 0 only) ----------------------
template<int MODE>
__global__ __launch_bounds__(256) void gather_k(const _Float16* __restrict__ X,
    int ldx, _Float16* __restrict__ Mout, const int* __restrict__ elist,
    const int* __restrict__ cnt, int N,
    const float* __restrict__ wfin, const float* __restrict__ bfin,
    float* __restrict__ out)
{
    int wv = blockIdx.x * 4 + (threadIdx.x >> 6);
    int l  = threadIdx.x & 63;
    if (wv >= N) return;

    const int eo   = l >> 4;
    const int e2   = eo & 1;
    const int half = l >> 5;
    const int c8   = (l & 15) * 8;

    int dr = cnt[(size_t)half * N + wv];
    int d  = dr < CAP ? dr : CAP;
    float inv = dr > 0 ? 1.f / (float)dr : 0.f;
    const int* lst = elist + ((size_t)half * N + wv) * CAP;

    float acc[8];
#pragma unroll
    for (int j = 0; j < 8; j++) acc[j] = 0.f;

    const f16x8 zv = {};
    for (int p = e2; p < d; p += 8) {
        int p1 = p + 2, p2 = p + 4, p3 = p + 6;
        int s0 = lst[p];
        f16x8 v0 = *(const f16x8*)&X[(size_t)s0 * ldx + c8];
        f16x8 v1 = zv, v2 = zv, v3 = zv;
        if (p1 < d) { int s = lst[p1]; v1 = *(const f16x8*)&X[(size_t)s * ldx + c8]; }
        if (p2 < d) { int s = lst[p2]; v2 = *(const f16x8*)&X[(size_t)s * ldx + c8]; }
        if (p3 < d) { int s = lst[p3]; v3 = *(const f16x8*)&X[(size_t)s * ldx + c8]; }
#pragma unroll
        for (int j = 0; j < 8; j++)
            acc[j] += (float)v0[j] + (float)v1[j] + (float)v2[j] + (float)v3[j];
    }

#pragma unroll
    for (int j = 0; j < 8; j++) {
        acc[j] += __shfl_xor(acc[j], 16);
        acc[j] *= inv;
    }

    if (MODE == 0) {
        if (eo == 0 || eo == 2) {
            f16x8 o;
#pragma unroll
            for (int j = 0; j < 8; j++) o[j] = (_Float16)acc[j];
            *(f16x8*)&Mout[(size_t)wv * 256 + half * 128 + c8] = o;
        }
    }
}

// ---------------- concat GEMM (fallback path, OUT != 3) --------------------------
__global__ __launch_bounds__(512) void gemm_cat(const _Float16* __restrict__ X1,
    const _Float16* __restrict__ Mt, const _Float16* __restrict__ WT,
    const float* __restrict__ bias, _Float16* __restrict__ X2, int M, int mtiles)
{
    const int w   = threadIdx.x >> 6;
    const int l   = threadIdx.x & 63;
    const int l15 = l & 15;
    const int q   = l >> 4;
    const int col = w * 16 + l15;

    f16x8 bf[12];
    {
        const _Float16* wpp = WT + (size_t)col * 384 + q * 8;
#pragma unroll
        for (int c = 0; c < 12; c++) bf[c] = *(const f16x8*)(wpp + c * 32);
    }
    const float bj = bias[col];

    int t = blockIdx.x;
    if (t >= mtiles) return;
    f16x8 xf[12];
    {
        const _Float16* xp = X1 + ((size_t)t * 16 + l15) * 128 + q * 8;
        const _Float16* mp = Mt + ((size_t)t * 16 + l15) * 256 + q * 8;
#pragma unroll
        for (int c = 0; c < 4; c++) xf[c] = *(const f16x8*)(xp + c * 32);
#pragma unroll
        for (int c = 4; c < 12; c++) xf[c] = *(const f16x8*)(mp + (c - 4) * 32);
    }

    const f32x4 z4 = {0.f, 0.f, 0.f, 0.f};
    while (true) {
        int tn = t + gridDim.x;
        bool more = tn < mtiles;
        f16x8 xnf[12];
        if (more) {
            const _Float16* xp = X1 + ((size_t)tn * 16 + l15) * 128 + q * 8;
            const _Float16* mp = Mt + ((size_t)tn * 16 + l15) * 256 + q * 8;
#pragma unroll
            for (int c = 0; c < 4; c++) xnf[c] = *(const f16x8*)(xp + c * 32);
#pragma unroll
            for (int c = 4; c < 12; c++) xnf[c] = *(const f16x8*)(mp + (c - 4) * 32);
        }

        f32x4 a0 = z4;
#pragma unroll
        for (int c = 0; c < 12; c++)
            a0 = __builtin_amdgcn_mfma_f32_16x16x32_f16(xf[c], bf[c], a0, 0, 0, 0);

#pragma unroll
        for (int rg = 0; rg < 4; rg++) {
            int row = t * 16 + q * 4 + rg;
            if (row < M) X2[(size_t)row * 128 + col] = (_Float16)(a0[rg] + bj);
        }
        if (!more) break;
        t = tn;
#pragma unroll
        for (int c = 0; c < 12; c++) xf[c] = xnf[c];
    }
}

// ---------------- generic projection fallback (OUT != 3) -------------------------
__global__ __launch_bounds__(256) void proj_generic(const _Float16* __restrict__ X2,
    const _Float16* __restrict__ Mt, const float* __restrict__ wfin,
    const float* __restrict__ bfin, float* __restrict__ out, int N, int OUT)
{
    int row = blockIdx.x * 4 + (threadIdx.x >> 6);
    int l = threadIdx.x & 63;
    if (row >= N) return;
    float xv[6];
#pragma unroll
    for (int i = 0; i < 6; i++) {
        int k = l * 6 + i;
        xv[i] = (k < 128) ? (float)X2[(size_t)row * 128 + k]
                          : (float)Mt[(size_t)row * 256 + (k - 128)];
    }
    for (int c = 0; c < OUT; c++) {
        float p = 0.f;
#pragma unroll
        for (int i = 0; i < 6; i++) p += xv[i] * wfin[(size_t)(l * 6 + i) * OUT + c];
        for (int off = 32; off > 0; off >>= 1) p += __shfl_down(p, off);
        if (l == 0) out[(size_t)row * OUT + c] = p + bfin[c];
    }
}

extern "C" void kernel_launch(void* const* d_in, const int* in_sizes, int n_in,
                              void* d_out, int out_size, void* d_ws, size_t ws_size,
                              hipStream_t stream) {
    const float* feature = (const float*)d_in[0];
    const int*   ei      = (const int*)d_in[1];   // [2,E]: src then dst
    const int*   et      = (const int*)d_in[2];   // [E]
    const float* w_in    = (const float*)d_in[3];
    const float* b_in    = (const float*)d_in[4];
    const float* w_rel   = (const float*)d_in[5];
    const float* w_root  = (const float*)d_in[6];
    const float* b_conv  = (const float*)d_in[7];
    const float* w_out   = (const float*)d_in[8];
    const float* b_out   = (const float*)d_in[9];

    const int HH   = in_sizes[4];                 // 128
    const int D_IN = in_sizes[3] / HH;            // 768
    const int N    = in_sizes[0] / D_IN;          // 50000
    const int E    = in_sizes[1] / 2;             // 600000
    const int OUT  = in_sizes[9];                 // 3

    // workspace layout (16B-aligned segments)
    char* base = (char*)d_ws;
    _Float16* wInT  = (_Float16*)base;                             // 768*128 packed
    _Float16* wcatT = wInT + (size_t)D_IN * HH;                    // 128*384
    _Float16* X1    = wcatT + (size_t)HH * 384;                    // N*128
    _Float16* X2    = X1 + (size_t)N * HH;                         // N*128 (fallback only)
    _Float16* Mt    = X2 + (size_t)N * HH;                         // N*256 (fallback only)
    float* Pt       = (float*)(Mt + (size_t)N * 256);              // N*12 fp32
    float* wfin     = Pt + (size_t)N * 12;                         // 3*128*OUT
    float* bfin     = wfin + (size_t)3 * HH * (OUT > 0 ? OUT : 1); // OUT
    int* cnt        = (int*)(bfin + ((OUT + 3) & ~3));             // 2N
    int* elist      = cnt + (size_t)2 * N;                         // 2N*CAP

    hipMemsetAsync(cnt, 0, sizeof(int) * (size_t)2 * N, stream);
    {
        int ptot = D_IN * HH + HH * 384 + 3 * HH * OUT + OUT;
        prep_all<<<(ptot + 255) / 256, 256, 0, stream>>>(
            w_in, w_root, w_rel, b_conv, w_out, b_out,
            wInT, wcatT, wfin, bfin, D_IN, OUT);
    }

    // combined launch: GEMM tiles first (long pole), hist blocks overlapped behind
    const int gemmBlocks = (N + 63) / 64;
    const int histBlocks = (E + 255) / 256;
    gemm_hist<<<gemmBlocks + histBlocks, 256, 0, stream>>>(
        feature, wInT, b_in, X1, N, D_IN, HH, gemmBlocks,
        ei, ei + E, et, cnt, elist, E, N);

    const int mtiles  = (N + 15) / 16;
    const int gblocks = (N + 3) / 4;

    if (OUT == 3) {
        // layer 1 GEMM-gather + layer-2 projection fused; then 16B/edge gather
        fused_l1<<<mtiles, 256, 0, stream>>>(X1, wcatT, b_conv, wfin,
                                             elist, cnt, Pt, N);
        gather_fin<<<(N + 255) / 256, 256, 0, stream>>>(Pt, elist, cnt, bfin,
                                                        (float*)d_out, N);
    } else {
        gather_k<0><<<gblocks, 256, 0, stream>>>(X1, 128, Mt, elist, cnt, N,
                                                 nullptr, nullptr, nullptr);
        gemm_cat<<<1024, 512, 0, stream>>>(X1, Mt, wcatT, b_conv, X2, N, mtiles);
        gather_k<0><<<gblocks, 256, 0, stream>>>(X2, 128, Mt, elist, cnt, N,
                                                 nullptr, nullptr, nullptr);
        proj_generic<<<gblocks, 256, 0, stream>>>(X2, Mt, wfin, bfin,
                                                  (float*)d_out, N, OUT);
    }
}